// Round 1
// baseline (16995.811 us; speedup 1.0000x reference)
//
#include <hip/hip_runtime.h>

#define NB 64      // batch
#define NS 1024    // seq len
#define NI 300     // input dim
#define NH 512     // hidden
#define XPAD 320   // padded x-part of layer0 K
#define K0 (XPAD + NH)   // 832  (26 * 32)
#define K1 (2 * NH)      // 1024 (32 * 32)
#define NWG 128
#define NL0 64           // layer-0 workgroups
#define WST0 840         // LDS row stride (halves), pad for bank spread
#define WST1 1032

typedef _Float16 f16;
typedef f16 half8 __attribute__((ext_vector_type(8)));
typedef float floatx4 __attribute__((ext_vector_type(4)));

__device__ __attribute__((aligned(16))) f16 g_Z0[2][NB][K0];  // [x_pad | h0]
__device__ __attribute__((aligned(16))) f16 g_Z1[2][NB][K1];  // [h0 | h1]
__device__ unsigned g_flags[NWG];  // zero-init (.bss); monotonic across calls

__device__ __forceinline__ float sigm(float x) { return 1.f / (1.f + __expf(-x)); }
__device__ __forceinline__ float tanhfast(float x) { return 1.f - 2.f / (__expf(2.f * x) + 1.f); }

__global__ void __launch_bounds__(256) lstm_persist(
    const float* __restrict__ xin,
    const float* __restrict__ Wih0, const float* __restrict__ Whh0,
    const float* __restrict__ bih0, const float* __restrict__ bhh0,
    const float* __restrict__ Wih1, const float* __restrict__ Whh1,
    const float* __restrict__ bih1, const float* __restrict__ bhh1,
    float* __restrict__ out)
{
  __shared__ f16 Wl[32 * WST1];      // 66048 B, per-WG weight slice (fp16)
  __shared__ float gbuf[64 * 33];    // gates staging, padded stride
  __shared__ float cst[NB * 8];      // cell state slice
  __shared__ float bias_s[32];

  const int wg = blockIdx.x;
  const int tid = threadIdx.x;
  const bool L1 = (wg >= NL0);
  const int j0 = (L1 ? wg - NL0 : wg) << 3;   // 8 hidden cols per WG
  const int K = L1 ? K1 : K0;
  const int WST = L1 ? WST1 : WST0;

  const unsigned base =
      __hip_atomic_load(&g_flags[wg], __ATOMIC_RELAXED, __HIP_MEMORY_SCOPE_AGENT);

  // ---------------- init: weights -> LDS (fp16), zero states, stage x_0 ----
  {
    const float* Wx = L1 ? Wih1 : Wih0;
    const float* Wh = L1 ? Whh1 : Whh0;
    const int xreal = L1 ? NH : NI;   // real x-part K
    const int xpad  = L1 ? NH : XPAD; // padded x-part K
    const int xw    = L1 ? NH : NI;   // Wx row width
    const int lc = tid >> 3, seg = tid & 7;
    const int gc = ((lc >> 3) * NH) + j0 + (lc & 7);  // gate row: {i,f,g,o} blocks
    const int per = K >> 3;
    for (int e = 0; e < per; ++e) {
      const int k = seg * per + e;
      float v;
      if (k < xreal)      v = Wx[(size_t)gc * xw + k];
      else if (k < xpad)  v = 0.f;
      else                v = Wh[(size_t)gc * NH + (k - xpad)];
      Wl[lc * WST + k] = (f16)v;
    }
    if (tid < 32) {
      const int gc2 = ((tid >> 3) * NH) + j0 + (tid & 7);
      bias_s[tid] = (L1 ? bih1 : bih0)[gc2] + (L1 ? bhh1 : bhh0)[gc2];
    }
    for (int i = tid; i < NB * 8; i += 256) cst[i] = 0.f;
    for (int i = tid; i < NB * 8; i += 256) {   // zero initial h slices
      const int b = i >> 3, lj = i & 7;
      if (!L1) g_Z0[0][b][XPAD + j0 + lj] = (f16)0.f;
      else     g_Z1[1][b][NH + j0 + lj]   = (f16)0.f;
    }
    if (!L1) {  // x_0 into Z0[0]; zero pad cols (300..319) in BOTH buffers
      const int c0 = wg * 5;
      for (int i = tid; i < NB * 5; i += 256) {
        const int b = i / 5, cc = i % 5;
        const int c = c0 + cc;
        if (c < NI) {
          g_Z0[0][b][c] = (f16)xin[(size_t)b * NS * NI + c];
        } else {
          g_Z0[0][b][c] = (f16)0.f;
          g_Z0[1][b][c] = (f16)0.f;
        }
      }
    }
  }
  __syncthreads();
  if (tid == 0) {
    __threadfence();
    __hip_atomic_store(&g_flags[wg], base + 1, __ATOMIC_RELEASE, __HIP_MEMORY_SCOPE_AGENT);
  }

  const int wv = tid >> 6, lane = tid & 63;
  const int r15 = lane & 15, kb = (lane >> 4) << 3;
  const int mpair = wv & 1, khalf = wv >> 1;

  // phases: t=0..1024; layer0 computes h0(t) for t<1024, layer1 computes h1(t-1) for t>=1
  for (int t = 0; t <= NS; ++t) {
    const unsigned target = base + 1 + (unsigned)t;
    if (tid < 64) {
      for (;;) {
        const unsigned fa = __hip_atomic_load(&g_flags[tid],      __ATOMIC_RELAXED, __HIP_MEMORY_SCOPE_AGENT);
        const unsigned fb = __hip_atomic_load(&g_flags[64 + tid], __ATOMIC_RELAXED, __HIP_MEMORY_SCOPE_AGENT);
        if (__all(fa >= target && fb >= target)) break;
        __builtin_amdgcn_s_sleep(2);
      }
      __threadfence();   // acquire: invalidate stale L1/L2 before reads
    }
    __syncthreads();

    const bool active = L1 ? (t >= 1) : (t < NS);
    if (active) {
      const f16* __restrict__ Z = L1 ? &g_Z1[t & 1][0][0] : &g_Z0[t & 1][0][0];
      const int nch = L1 ? 32 : 26;
      const int hch = nch >> 1;
      const int cbeg = khalf * hch, cend = cbeg + hch;
      floatx4 acc00 = {0.f,0.f,0.f,0.f}, acc01 = {0.f,0.f,0.f,0.f};
      floatx4 acc10 = {0.f,0.f,0.f,0.f}, acc11 = {0.f,0.f,0.f,0.f};
      const f16* A0 = Z + (size_t)((mpair << 5) + r15) * K + kb;  // batch rows
      const f16* A1 = A0 + (size_t)16 * K;
      const f16* B0 = &Wl[r15 * WST + kb];          // N-tile 0: {i|f} cols
      const f16* B1 = &Wl[(16 + r15) * WST + kb];   // N-tile 1: {g|o} cols
      for (int ch = cbeg; ch < cend; ++ch) {
        const int k = ch << 5;
        half8 a0 = *(const half8*)(A0 + k);
        half8 a1 = *(const half8*)(A1 + k);
        half8 b0 = *(const half8*)(B0 + k);
        half8 b1 = *(const half8*)(B1 + k);
        acc00 = __builtin_amdgcn_mfma_f32_16x16x32_f16(a0, b0, acc00, 0, 0, 0);
        acc10 = __builtin_amdgcn_mfma_f32_16x16x32_f16(a1, b0, acc10, 0, 0, 0);
        acc01 = __builtin_amdgcn_mfma_f32_16x16x32_f16(a0, b1, acc01, 0, 0, 0);
        acc11 = __builtin_amdgcn_mfma_f32_16x16x32_f16(a1, b1, acc11, 0, 0, 0);
      }
      // K-half reduce into gbuf. C/D layout: col = lane&15, row = (lane>>4)*4 + r
      const int rbase = (mpair << 5) + ((lane >> 4) << 2);
      if (khalf == 0) {
        #pragma unroll
        for (int r = 0; r < 4; ++r) {
          gbuf[(rbase + r) * 33 + r15]            = acc00[r];
          gbuf[(rbase + 16 + r) * 33 + r15]       = acc10[r];
          gbuf[(rbase + r) * 33 + 16 + r15]       = acc01[r];
          gbuf[(rbase + 16 + r) * 33 + 16 + r15]  = acc11[r];
        }
      }
      __syncthreads();
      if (khalf == 1) {
        #pragma unroll
        for (int r = 0; r < 4; ++r) {
          gbuf[(rbase + r) * 33 + r15]           += acc00[r];
          gbuf[(rbase + 16 + r) * 33 + r15]      += acc10[r];
          gbuf[(rbase + r) * 33 + 16 + r15]      += acc01[r];
          gbuf[(rbase + 16 + r) * 33 + 16 + r15] += acc11[r];
        }
      }
      __syncthreads();

      // epilogue: gates -> (h, c); 512 (b,j) pairs, 2 per thread
      const int nb2 = (t + 1) & 1;
      #pragma unroll
      for (int p = 0; p < 2; ++p) {
        const int idx = (tid << 1) + p;
        const int b = idx >> 3, lj = idx & 7;
        const float gi = gbuf[b * 33 + lj]        + bias_s[lj];
        const float gf = gbuf[b * 33 + 8 + lj]    + bias_s[8 + lj];
        const float gg = gbuf[b * 33 + 16 + lj]   + bias_s[16 + lj];
        const float go = gbuf[b * 33 + 24 + lj]   + bias_s[24 + lj];
        const float cold = cst[(b << 3) + lj];
        const float cn = sigm(gf) * cold + sigm(gi) * tanhfast(gg);
        const float hn = sigm(go) * tanhfast(cn);
        cst[(b << 3) + lj] = cn;
        if (!L1) {
          g_Z0[nb2][b][XPAD + j0 + lj] = (f16)hn;
          g_Z1[nb2][b][j0 + lj]        = (f16)hn;
        } else {
          const int s = t - 1;
          g_Z1[nb2][b][NH + j0 + lj] = (f16)hn;
          out[(size_t)b * NS * NH + (size_t)s * NH + j0 + lj] = hn;
          out[(size_t)NB * NS * NH + (size_t)b * NS * NH + (size_t)s * NH + j0 + lj] = cn;
          if (t == NS) {
            out[(size_t)2 * NB * NS * NH + (size_t)b * NH + j0 + lj] = hn;
            out[(size_t)2 * NB * NS * NH + (size_t)NB * NH + (size_t)b * NH + j0 + lj] = cn;
          }
        }
      }
    }

    // stage x_{t+1} into the next buffer (layer-0 WGs)
    if (!L1 && (t + 1) < NS) {
      const int c0 = wg * 5;
      const int nb2 = (t + 1) & 1;
      for (int i = tid; i < NB * 5; i += 256) {
        const int b = i / 5, cc = i % 5;
        const int c = c0 + cc;
        if (c < NI)
          g_Z0[nb2][b][c] = (f16)xin[(size_t)b * NS * NI + (size_t)(t + 1) * NI + c];
      }
    }

    __syncthreads();   // drain all stores (vmcnt0) before signaling
    if (tid == 0) {
      __threadfence();  // release: writeback L2 to coherence point
      __hip_atomic_store(&g_flags[wg], base + 2 + (unsigned)t, __ATOMIC_RELEASE, __HIP_MEMORY_SCOPE_AGENT);
    }
  }
}

extern "C" void kernel_launch(void* const* d_in, const int* in_sizes, int n_in,
                              void* d_out, int out_size, void* d_ws, size_t ws_size,
                              hipStream_t stream) {
  (void)in_sizes; (void)n_in; (void)d_ws; (void)ws_size; (void)out_size;
  lstm_persist<<<dim3(NWG), dim3(256), 0, stream>>>(
      (const float*)d_in[0],
      (const float*)d_in[1], (const float*)d_in[2],
      (const float*)d_in[3], (const float*)d_in[4],
      (const float*)d_in[5], (const float*)d_in[6],
      (const float*)d_in[7], (const float*)d_in[8],
      (float*)d_out);
}

// Round 2
// 12499.459 us; speedup vs baseline: 1.3597x; 1.3597x over previous
//
#include <hip/hip_runtime.h>

#define NB 64      // batch
#define NS 1024    // seq len
#define NI 300     // input dim
#define NH 512     // hidden
#define NWG 128
#define NL0 64     // layer-0 workgroups

typedef _Float16 f16;
typedef f16 half8 __attribute__((ext_vector_type(8)));
typedef float floatx4 __attribute__((ext_vector_type(4)));
typedef unsigned long long u64;
typedef unsigned int u32;

// x prestaged as f16, K-padded 300->320: [t][b][80 u64 = 320 halves]
__device__ u64 g_X[NS][NB][80];
// h state double buffers (512 f16 = 128 u64 per row), exchanged coherently
__device__ u64 g_H0[2][NB][128];
__device__ u64 g_H1[2][NB][128];
__device__ u32 g_flags[NWG];   // zero-init .bss; monotonic across replays

__device__ __forceinline__ float sigm(float x){ return 1.f/(1.f+__expf(-x)); }
__device__ __forceinline__ float tanh_(float x){ return 1.f - 2.f/(__expf(2.f*x)+1.f); }

__device__ __forceinline__ u64 cload(const u64* p){
  return __hip_atomic_load(p, __ATOMIC_RELAXED, __HIP_MEMORY_SCOPE_AGENT);
}
__device__ __forceinline__ void cstore32(u32* p, u32 v){
  __hip_atomic_store(p, v, __ATOMIC_RELAXED, __HIP_MEMORY_SCOPE_AGENT);
}
__device__ __forceinline__ void cstore64(u64* p, u64 v){
  __hip_atomic_store(p, v, __ATOMIC_RELAXED, __HIP_MEMORY_SCOPE_AGENT);
}

union H8U { u64 u[2]; half8 h; };

__device__ __forceinline__ void phase_wait(int tid, u32 target){
  if (tid < 64) {
    for(;;){
      const u32 fa = __hip_atomic_load(&g_flags[tid],    __ATOMIC_RELAXED, __HIP_MEMORY_SCOPE_AGENT);
      const u32 fb = __hip_atomic_load(&g_flags[64+tid], __ATOMIC_RELAXED, __HIP_MEMORY_SCOPE_AGENT);
      if (__all(((int)(fa - target) >= 0) && ((int)(fb - target) >= 0))) break;
      __builtin_amdgcn_s_sleep(1);
    }
  }
  __syncthreads();
}

__device__ __forceinline__ void phase_signal(int wg, int tid, u32 val){
  __syncthreads();   // all waves drain their vmem (compiler emits vmcnt(0) before s_barrier)
  if (tid == 0) {
    asm volatile("s_waitcnt vmcnt(0)" ::: "memory");
    __hip_atomic_store(&g_flags[wg], val, __ATOMIC_RELAXED, __HIP_MEMORY_SCOPE_AGENT);
  }
}

template<bool IS_L1, int CH0, int NCH2>
__device__ __forceinline__ void load_weights(
    const float* __restrict__ Wx, const float* __restrict__ Wh,
    int j0, int r15, int kb, half8 (&w0)[NCH2], half8 (&w1)[NCH2])
{
  #pragma unroll
  for (int ci = 0; ci < NCH2; ++ci){
    const int ch = CH0 + ci;
    #pragma unroll
    for (int tile = 0; tile < 2; ++tile){
      const int wrow = tile*16 + r15;
      const int gc = (wrow>>3)*NH + j0 + (wrow&7);   // gate rows: i,f | g,o
      union { f16 e[8]; half8 v; } tmp;
      #pragma unroll
      for (int j = 0; j < 8; ++j){
        const int k = ch*32 + kb + j;
        float v;
        if (IS_L1) v = (k < NH) ? Wx[(size_t)gc*NH + k] : Wh[(size_t)gc*NH + (k-NH)];
        else       v = (k < NI) ? Wx[(size_t)gc*NI + k]
                                : ((k < 320) ? 0.f : Wh[(size_t)gc*NH + (k-320)]);
        tmp.e[j] = (f16)v;
      }
      if (tile == 0) w0[ci] = tmp.v; else w1[ci] = tmp.v;
    }
  }
}

template<bool IS_L1, int CH0, int NCH2>
__device__ __forceinline__ void do_chains(
    int t, int row0, int row1, int kb,
    const half8 (&w0)[NCH2], const half8 (&w1)[NCH2],
    floatx4& acc00, floatx4& acc01, floatx4& acc10, floatx4& acc11)
{
  const int bufi = t & 1;
  #pragma unroll
  for (int ci = 0; ci < NCH2; ++ci){
    const int ch = CH0 + ci;            // compile-time after unroll
    const int hoff = ch*32 + kb;        // half-offset within K
    H8U a0, a1;
    if (!IS_L1 && ch < 10) {            // x part: normal cached loads
      const u64* p0 = &g_X[t][row0][0] + (hoff>>2);
      const u64* p1 = &g_X[t][row1][0] + (hoff>>2);
      a0.u[0] = p0[0]; a0.u[1] = p0[1];
      a1.u[0] = p1[0]; a1.u[1] = p1[1];
    } else if (!IS_L1 || ch < 16) {     // h0 part: coherent
      const int ho = IS_L1 ? hoff : (hoff - 320);
      const u64* base = &g_H0[bufi][0][0];
      a0.u[0] = cload(base + row0*128 + (ho>>2));
      a0.u[1] = cload(base + row0*128 + (ho>>2) + 1);
      a1.u[0] = cload(base + row1*128 + (ho>>2));
      a1.u[1] = cload(base + row1*128 + (ho>>2) + 1);
    } else {                            // h1 part: coherent
      const int ho = hoff - 512;
      const u64* base = &g_H1[bufi][0][0];
      a0.u[0] = cload(base + row0*128 + (ho>>2));
      a0.u[1] = cload(base + row0*128 + (ho>>2) + 1);
      a1.u[0] = cload(base + row1*128 + (ho>>2));
      a1.u[1] = cload(base + row1*128 + (ho>>2) + 1);
    }
    acc00 = __builtin_amdgcn_mfma_f32_16x16x32_f16(a0.h, w0[ci], acc00, 0, 0, 0);
    acc10 = __builtin_amdgcn_mfma_f32_16x16x32_f16(a1.h, w0[ci], acc10, 0, 0, 0);
    acc01 = __builtin_amdgcn_mfma_f32_16x16x32_f16(a0.h, w1[ci], acc01, 0, 0, 0);
    acc11 = __builtin_amdgcn_mfma_f32_16x16x32_f16(a1.h, w1[ci], acc11, 0, 0, 0);
  }
}

template<bool IS_L1>
__device__ __forceinline__ void run_lstm(
    const float* __restrict__ Wx, const float* __restrict__ Wh,
    float* __restrict__ out, float* gbuf, float* cst, const float* bias_s,
    int wg, int tid, u32 base)
{
  const int wv = tid >> 6, lane = tid & 63;
  const int r15 = lane & 15, kb = (lane >> 4) << 3;
  const int mpair = wv & 1, khalf = wv >> 1;
  const int j0 = (IS_L1 ? wg - NL0 : wg) << 3;

  constexpr int NCH2 = IS_L1 ? 16 : 13;
  half8 w0[NCH2], w1[NCH2];
  if (khalf == 0) load_weights<IS_L1, 0,     NCH2>(Wx, Wh, j0, r15, kb, w0, w1);
  else            load_weights<IS_L1, NCH2,  NCH2>(Wx, Wh, j0, r15, kb, w0, w1);

  for (int t = 0; t <= NS; ++t){
    phase_wait(tid, base + 1 + (u32)t);
    const bool active = IS_L1 ? (t >= 1) : (t < NS);
    if (active){
      floatx4 acc00 = {0.f,0.f,0.f,0.f}, acc01 = {0.f,0.f,0.f,0.f};
      floatx4 acc10 = {0.f,0.f,0.f,0.f}, acc11 = {0.f,0.f,0.f,0.f};
      const int row0 = (mpair << 5) + r15, row1 = row0 + 16;
      if (khalf == 0) do_chains<IS_L1, 0,    NCH2>(t, row0, row1, kb, w0, w1, acc00, acc01, acc10, acc11);
      else            do_chains<IS_L1, NCH2, NCH2>(t, row0, row1, kb, w0, w1, acc00, acc01, acc10, acc11);

      // K-half reduce into gbuf. C/D layout: col = lane&15, row = (lane>>4)*4 + r
      const int rbase = (mpair << 5) + ((lane >> 4) << 2);
      if (khalf == 0) {
        #pragma unroll
        for (int r = 0; r < 4; ++r) {
          gbuf[(rbase + r) * 33 + r15]            = acc00[r];
          gbuf[(rbase + 16 + r) * 33 + r15]       = acc10[r];
          gbuf[(rbase + r) * 33 + 16 + r15]       = acc01[r];
          gbuf[(rbase + 16 + r) * 33 + 16 + r15]  = acc11[r];
        }
      }
      __syncthreads();
      if (khalf == 1) {
        #pragma unroll
        for (int r = 0; r < 4; ++r) {
          gbuf[(rbase + r) * 33 + r15]           += acc00[r];
          gbuf[(rbase + 16 + r) * 33 + r15]      += acc10[r];
          gbuf[(rbase + r) * 33 + 16 + r15]      += acc01[r];
          gbuf[(rbase + 16 + r) * 33 + 16 + r15] += acc11[r];
        }
      }
      __syncthreads();

      // epilogue: 512 (b,j) pairs, 2 adjacent-j per thread
      const int nb2 = (t + 1) & 1;
      const int b = tid >> 2, lj0 = (tid << 1) & 7;
      float hn2[2], cn2[2];
      #pragma unroll
      for (int p = 0; p < 2; ++p){
        const int lj = lj0 + p;
        const float gi = gbuf[b*33 + lj]      + bias_s[lj];
        const float gf = gbuf[b*33 + 8 + lj]  + bias_s[8 + lj];
        const float gg = gbuf[b*33 + 16 + lj] + bias_s[16 + lj];
        const float go = gbuf[b*33 + 24 + lj] + bias_s[24 + lj];
        const float cold = cst[(b << 3) + lj];
        const float cn = sigm(gf) * cold + sigm(gi) * tanh_(gg);
        const float hn = sigm(go) * tanh_(cn);
        cst[(b << 3) + lj] = cn;
        hn2[p] = hn; cn2[p] = cn;
      }
      union { f16 e[2]; u32 u; } pk;
      pk.e[0] = (f16)hn2[0]; pk.e[1] = (f16)hn2[1];
      u32* hrow = (u32*)(IS_L1 ? &g_H1[nb2][b][0] : &g_H0[nb2][b][0]);
      cstore32(hrow + ((j0 + lj0) >> 1), pk.u);
      if (IS_L1){
        const int s = t - 1;
        const size_t o1 = (size_t)b*NS*NH + (size_t)s*NH + j0 + lj0;
        *(float2*)&out[o1] = float2{hn2[0], hn2[1]};
        *(float2*)&out[(size_t)NB*NS*NH + o1] = float2{cn2[0], cn2[1]};
        if (t == NS){
          const size_t o2 = (size_t)2*NB*NS*NH + (size_t)b*NH + j0 + lj0;
          *(float2*)&out[o2] = float2{hn2[0], hn2[1]};
          *(float2*)&out[o2 + (size_t)NB*NH] = float2{cn2[0], cn2[1]};
        }
      }
    }
    phase_signal(wg, tid, base + 2 + (u32)t);
  }
}

__global__ void __launch_bounds__(256) lstm_persist(
    const float* __restrict__ xin,
    const float* __restrict__ Wih0, const float* __restrict__ Whh0,
    const float* __restrict__ bih0, const float* __restrict__ bhh0,
    const float* __restrict__ Wih1, const float* __restrict__ Whh1,
    const float* __restrict__ bih1, const float* __restrict__ bhh1,
    float* __restrict__ out)
{
  __shared__ float gbuf[64 * 33];
  __shared__ float cst[NB * 8];
  __shared__ float bias_s[32];

  const int wg = blockIdx.x;
  const int tid = threadIdx.x;
  const bool L1 = (wg >= NL0);
  const int j0 = (L1 ? wg - NL0 : wg) << 3;

  const u32 base =
      __hip_atomic_load(&g_flags[wg], __ATOMIC_RELAXED, __HIP_MEMORY_SCOPE_AGENT);

  // ---- init ----
  if (tid < 32){
    const int gc2 = ((tid >> 3) * NH) + j0 + (tid & 7);
    bias_s[tid] = (L1 ? bih1 : bih0)[gc2] + (L1 ? bhh1 : bhh0)[gc2];
  }
  for (int i = tid; i < NB * 8; i += 256) cst[i] = 0.f;

  // zero the h buffer that phase 0/1 reads (coherent stores)
  if (!L1) { if (tid < 128) cstore64(&g_H0[0][wg][tid], 0ull); }
  else     { if (tid < 128) cstore64(&g_H1[1][wg - NL0][tid], 0ull); }

  // prestage x -> f16 (padded to 320); each WG handles 8 timesteps
  {
    const int b = tid >> 2, q = tid & 3;
    for (int r = 0; r < 8; ++r){
      const int t = wg + (r << 7);
      const float* xr = xin + ((size_t)b * NS + t) * NI;
      u64* dst = &g_X[t][b][0];
      for (int e = 0; e < 20; ++e){
        const int idx = q * 20 + e;     // u64 index; 4 halves each
        u64 v = 0;
        if (idx < 75){                  // 300/4 = 75 real u64s
          const float4 f = *(const float4*)(xr + (idx << 2));
          union { f16 h[4]; u64 u; } pkx;
          pkx.h[0] = (f16)f.x; pkx.h[1] = (f16)f.y;
          pkx.h[2] = (f16)f.z; pkx.h[3] = (f16)f.w;
          v = pkx.u;
        }
        dst[idx] = v;
      }
    }
  }
  __syncthreads();
  if (tid == 0){
    __threadfence();   // one-time: publish normal-cached g_X stores
    __hip_atomic_store(&g_flags[wg], base + 1, __ATOMIC_RELEASE, __HIP_MEMORY_SCOPE_AGENT);
  }

  if (L1) run_lstm<true >(Wih1, Whh1, out, gbuf, cst, bias_s, wg, tid, base);
  else    run_lstm<false>(Wih0, Whh0, out, gbuf, cst, bias_s, wg, tid, base);
}

extern "C" void kernel_launch(void* const* d_in, const int* in_sizes, int n_in,
                              void* d_out, int out_size, void* d_ws, size_t ws_size,
                              hipStream_t stream) {
  (void)in_sizes; (void)n_in; (void)d_ws; (void)ws_size; (void)out_size;
  lstm_persist<<<dim3(NWG), dim3(256), 0, stream>>>(
      (const float*)d_in[0],
      (const float*)d_in[1], (const float*)d_in[2],
      (const float*)d_in[3], (const float*)d_in[4],
      (const float*)d_in[5], (const float*)d_in[6],
      (const float*)d_in[7], (const float*)d_in[8],
      (float*)d_out);
}

// Round 3
// 8661.377 us; speedup vs baseline: 1.9623x; 1.4431x over previous
//
#include <hip/hip_runtime.h>

#define NB 64
#define NS 1024
#define NI 300
#define NH 512
#define NWG 224
#define L0N 64
#define L1N 128

typedef _Float16 f16;
typedef f16 half8 __attribute__((ext_vector_type(8)));
typedef float floatx4 __attribute__((ext_vector_type(4)));
typedef unsigned long long u64;
typedef unsigned u32;

__device__ __attribute__((aligned(64))) f16   g_X[NS][NB][320];   // x, f16, K-padded
__device__ __attribute__((aligned(64))) f16   g_H0[4][NB][NH];    // h0 ring
__device__ __attribute__((aligned(64))) f16   g_H1[4][NB][NH];    // h1 ring
__device__ __attribute__((aligned(64))) float g_C1[4][NB][NH];    // c1 ring (fp32)
__device__ u32 g_flags[NWG];   // zero-init .bss; monotonic across replays

__device__ __forceinline__ float sigm(float x){ return 1.f/(1.f+__expf(-x)); }
__device__ __forceinline__ float tanh_(float x){ return 1.f - 2.f/(__expf(2.f*x)+1.f); }

__device__ __forceinline__ u32 ld_flag(int i){
  return __hip_atomic_load(&g_flags[i], __ATOMIC_RELAXED, __HIP_MEMORY_SCOPE_AGENT);
}
__device__ __forceinline__ void sig_flag(int i, u32 v){
  __hip_atomic_store(&g_flags[i], v, __ATOMIC_RELAXED, __HIP_MEMORY_SCOPE_AGENT);
}

#define STR_(x) #x
#define STR(x) STR_(x)
#define CLOAD16(dst, base, OFF) \
  asm volatile("global_load_dwordx4 %0, %1, off offset:" STR(OFF) " sc0 sc1" \
               : "=v"(dst) : "v"(base))
#define CLOAD8(dst, base) \
  asm volatile("global_load_dwordx2 %0, %1, off sc0 sc1" : "=v"(dst) : "v"(base))
#define CLOADF4(dst, base) \
  asm volatile("global_load_dwordx4 %0, %1, off sc0 sc1" : "=v"(dst) : "v"(base))
#define CSTORE16(base, val) \
  asm volatile("global_store_dwordx4 %0, %1, off sc0 sc1" :: "v"(base), "v"(val))
#define CSTORE8(base, val) \
  asm volatile("global_store_dwordx2 %0, %1, off sc0 sc1" :: "v"(base), "v"(val))
#define VWAIT(N) do { asm volatile("s_waitcnt vmcnt(" STR(N) ")" ::: "memory"); \
  __builtin_amdgcn_sched_barrier(0); } while(0)
#define MFMA(acc, a, b) acc = __builtin_amdgcn_mfma_f32_16x16x32_f16(a, b, acc, 0, 0, 0)

__global__ void __launch_bounds__(256, 1) lstm_persist(
    const float* __restrict__ xin,
    const float* __restrict__ Wih0, const float* __restrict__ Whh0,
    const float* __restrict__ bih0, const float* __restrict__ bhh0,
    const float* __restrict__ Wih1, const float* __restrict__ Whh1,
    const float* __restrict__ bih1, const float* __restrict__ bhh1,
    float* __restrict__ out)
{
  __shared__ f16   Wl[16 * 840];        // L0: tile1 weights (840-stride); L1: 264-stride slice
  __shared__ f16   sh_h[4][16][8];
  __shared__ float sh_c[4][16][4];
  __shared__ char  lds_pad[84000];      // force 1 WG/CU

  const int wg = blockIdx.x, tid = threadIdx.x;
  const int wv = tid >> 6, lane = tid & 63, r15 = lane & 15, g4 = lane >> 4;
  const int kb = g4 * 8;                // half-offset within 32-chain
  const u32 base = ld_flag(wg);
  if (__builtin_expect(base == 0xdeadbeefu, 0)) ((volatile char*)lds_pad)[tid] = 1;

  if (wg < L0N) {
    // ================= LAYER 0 (64 WGs, 8 hidden cols) =================
    const int j0 = wg * 8;
    const int mrow = wv * 16 + r15;
    // ---- init: x prestage (16 timesteps per WG) ----
    {
      const int b = tid >> 2, q = tid & 3;
      for (int r = 0; r < 16; ++r) {
        const int t = wg * 16 + r;
        const float* xr = xin + ((size_t)b * NS + t) * NI;
        u64* dst = (u64*)&g_X[t][b][0];
        #pragma unroll
        for (int e = 0; e < 20; ++e) {
          const int idx = q * 20 + e;
          u64 v = 0;
          if (idx < 75) {
            const float4 f = *(const float4*)(xr + (idx << 2));
            union { f16 h[4]; u64 u; } pk;
            pk.h[0]=(f16)f.x; pk.h[1]=(f16)f.y; pk.h[2]=(f16)f.z; pk.h[3]=(f16)f.w;
            v = pk.u;
          }
          dst[idx] = v;
        }
      }
    }
    // zero h0 ring slot 3 (read at t=0)
    if (tid < 64) { half8 z = {}; CSTORE16(&g_H0[3][tid][j0], z); }
    // tile0 weights (gates i,f) -> regs
    half8 w0[26];
    {
      const int gc = ((r15 >> 3) * NH) + j0 + (r15 & 7);
      #pragma unroll
      for (int ch = 0; ch < 26; ++ch) {
        union { f16 h[8]; half8 v; } pk;
        #pragma unroll
        for (int jj = 0; jj < 8; ++jj) {
          const int k = ch * 32 + kb + jj;
          const float v = (k < NI) ? Wih0[(size_t)gc * NI + k]
                         : (k < 320) ? 0.f : Whh0[(size_t)gc * NH + (k - 320)];
          pk.h[jj] = (f16)v;
        }
        w0[ch] = pk.v;
      }
    }
    // tile1 weights (gates g,o) -> LDS (stride 840)
    for (int r = 0; r < 16; ++r) {
      const int gc = (2 + (r >> 3)) * NH + j0 + (r & 7);
      for (int k = tid; k < 832; k += 256) {
        const float v = (k < NI) ? Wih0[(size_t)gc * NI + k]
                       : (k < 320) ? 0.f : Whh0[(size_t)gc * NH + (k - 320)];
        Wl[r * 840 + k] = (f16)v;
      }
    }
    const int jb = j0 + (r15 & 7);
    const float bi = bih0[jb] + bhh0[jb];
    const float bf = bih0[NH + jb] + bhh0[NH + jb];
    const float bg = bih0[2*NH + jb] + bhh0[2*NH + jb];
    const float bo = bih0[3*NH + jb] + bhh0[3*NH + jb];
    VWAIT(0);
    __syncthreads();
    if (tid == 0) { __threadfence(); sig_flag(wg, base + 1); }

    // initial poll (t=0): x + h0 slot3 ready when all L0 inited
    {
      const u32 T0 = base + 1;
      if (tid < 64) {
        for (;;) {
          const u32 f0 = ld_flag(tid);
          if (__all((int)(f0 - T0) >= 0)) break;
          __builtin_amdgcn_s_sleep(1);
        }
      }
      __syncthreads();
    }

    half8 xa[10];
    #pragma unroll
    for (int ci = 0; ci < 10; ++ci)
      xa[ci] = *(const half8*)&g_X[0][mrow][ci * 32 + kb];

    float creg[2] = {0.f, 0.f};
    const int hi = (r15 >> 3) & 1;
    const f16* wl = &Wl[r15 * 840 + kb];

    for (int t = 0; t < NS; ++t) {
      if (t > 0) {
        const u32 T0 = base + 1 + (u32)t;
        const u32 T1 = (t >= 4) ? (base + (u32)(t - 2)) : base;  // L1 done t-4 (h0 ring)
        if (tid < 64) {
          for (;;) {
            const u32 f0 = ld_flag(tid);
            const u32 fa = ld_flag(64 + tid);
            const u32 fb = ld_flag(128 + tid);
            const bool ok = ((int)(f0 - T0) >= 0) & ((int)(fa - T1) >= 0) & ((int)(fb - T1) >= 0);
            if (__all(ok)) break;
            __builtin_amdgcn_s_sleep(1);
          }
        }
        __syncthreads();
      }
      // issue 16 coherent h-loads (h0(t-1), slot (t+3)&3)
      const f16* hp = &g_H0[(t + 3) & 3][mrow][kb];
      half8 ha[16];
      CLOAD16(ha[0],  hp, 0);   CLOAD16(ha[1],  hp, 64);
      CLOAD16(ha[2],  hp, 128); CLOAD16(ha[3],  hp, 192);
      CLOAD16(ha[4],  hp, 256); CLOAD16(ha[5],  hp, 320);
      CLOAD16(ha[6],  hp, 384); CLOAD16(ha[7],  hp, 448);
      CLOAD16(ha[8],  hp, 512); CLOAD16(ha[9],  hp, 576);
      CLOAD16(ha[10], hp, 640); CLOAD16(ha[11], hp, 704);
      CLOAD16(ha[12], hp, 768); CLOAD16(ha[13], hp, 832);
      CLOAD16(ha[14], hp, 896); CLOAD16(ha[15], hp, 960);

      floatx4 a0a = {0,0,0,0}, a0b = {0,0,0,0}, a1a = {0,0,0,0}, a1b = {0,0,0,0};
      // x-chains in the shadow of h-load latency
      #pragma unroll
      for (int ci = 0; ci < 10; ++ci) {
        const half8 wb = *(const half8*)(wl + ci * 32);
        if (ci & 1) { MFMA(a0b, xa[ci], w0[ci]); MFMA(a1b, xa[ci], wb); }
        else        { MFMA(a0a, xa[ci], w0[ci]); MFMA(a1a, xa[ci], wb); }
      }
      VWAIT(8);
      #pragma unroll
      for (int ci = 0; ci < 8; ++ci) {
        const half8 wb = *(const half8*)(wl + (10 + ci) * 32);
        if (ci & 1) { MFMA(a0b, ha[ci], w0[10 + ci]); MFMA(a1b, ha[ci], wb); }
        else        { MFMA(a0a, ha[ci], w0[10 + ci]); MFMA(a1a, ha[ci], wb); }
      }
      VWAIT(0);
      #pragma unroll
      for (int ci = 8; ci < 16; ++ci) {
        const half8 wb = *(const half8*)(wl + (10 + ci) * 32);
        if (ci & 1) { MFMA(a0b, ha[ci], w0[10 + ci]); MFMA(a1b, ha[ci], wb); }
        else        { MFMA(a0a, ha[ci], w0[10 + ci]); MFMA(a1a, ha[ci], wb); }
      }
      const floatx4 acc0 = a0a + a0b, acc1 = a1a + a1b;

      // epilogue: lanes r15<8 rows {0,1}, r15>=8 rows {2,3}
      float f0v[4], f1v[4];
      #pragma unroll
      for (int r = 0; r < 4; ++r) {
        f0v[r] = __shfl_xor(acc0[r], 8, 64);
        f1v[r] = __shfl_xor(acc1[r], 8, 64);
      }
      #pragma unroll
      for (int p = 0; p < 2; ++p) {
        const float vi = (hi ? f0v[2+p] : (float)acc0[p]) + bi;
        const float vf = (hi ? (float)acc0[2+p] : f0v[p]) + bf;
        const float vg = (hi ? f1v[2+p] : (float)acc1[p]) + bg;
        const float vo = (hi ? (float)acc1[2+p] : f1v[p]) + bo;
        const float cn = sigm(vf) * creg[p] + sigm(vi) * tanh_(vg);
        const float hn = sigm(vo) * tanh_(cn);
        creg[p] = cn;
        sh_h[wv][g4 * 4 + hi * 2 + p][r15 & 7] = (f16)hn;
      }
      if (lane < 16) {
        const half8 hv = *(const half8*)&sh_h[wv][lane][0];
        CSTORE16(&g_H0[t & 3][wv * 16 + lane][j0], hv);
      }
      VWAIT(0);
      __syncthreads();
      if (tid == 0) sig_flag(wg, base + 2 + (u32)t);
      // prefetch next x (hidden under next poll)
      if (t + 1 < NS) {
        #pragma unroll
        for (int ci = 0; ci < 10; ++ci)
          xa[ci] = *(const half8*)&g_X[t + 1][mrow][ci * 32 + kb];
      }
    }

  } else if (wg < L0N + L1N) {
    // ================= LAYER 1 (128 WGs, 4 hidden cols) =================
    const int j0 = (wg - L0N) * 4;
    const int mrow = wv * 16 + r15;
    if (tid < 64) {
      u64 z = 0;
      CSTORE8(&g_H1[3][tid][j0], z);
    }
    half8 w1[24];
    {
      const int gc = (r15 >> 2) * NH + j0 + (r15 & 3);
      #pragma unroll
      for (int ch = 0; ch < 24; ++ch) {
        union { f16 h[8]; half8 v; } pk;
        #pragma unroll
        for (int jj = 0; jj < 8; ++jj) {
          const int k = ch * 32 + kb + jj;
          const float v = (k < NH) ? Wih1[(size_t)gc * NH + k]
                                   : Whh1[(size_t)gc * NH + (k - NH)];
          pk.h[jj] = (f16)v;
        }
        w1[ch] = pk.v;
      }
    }
    // h1 chains 8..15 -> LDS (stride 264)
    for (int r = 0; r < 16; ++r) {
      const int gc = (r >> 2) * NH + j0 + (r & 3);
      for (int k = tid; k < 256; k += 256)
        Wl[r * 264 + k] = (f16)Whh1[(size_t)gc * NH + 256 + k];
    }
    const int jb = j0 + (r15 & 3);
    const float bi = bih1[jb] + bhh1[jb];
    const float bf = bih1[NH + jb] + bhh1[NH + jb];
    const float bg = bih1[2*NH + jb] + bhh1[2*NH + jb];
    const float bo = bih1[3*NH + jb] + bhh1[3*NH + jb];
    VWAIT(0);
    __syncthreads();
    if (tid == 0) { __threadfence(); sig_flag(wg, base + 1); }

    float creg[2] = {0.f, 0.f};
    const f16* wl1 = &Wl[r15 * 264 + kb];

    for (int t = 0; t < NS; ++t) {
      {
        const u32 T0 = base + 2 + (u32)t;          // L0 done step t
        const u32 T1 = base + 1 + (u32)t;          // L1 done step t-1
        const u32 T2 = (t >= 4) ? (base + (u32)(t - 2)) : base;  // OUT done t-4
        if (tid < 64) {
          for (;;) {
            const u32 f0 = ld_flag(tid);
            const u32 fa = ld_flag(64 + tid);
            const u32 fb = ld_flag(128 + tid);
            const u32 fo = ld_flag(192 + (tid & 31));
            const bool ok = ((int)(f0 - T0) >= 0) & ((int)(fa - T1) >= 0) &
                            ((int)(fb - T1) >= 0) & ((int)(fo - T2) >= 0);
            if (__all(ok)) break;
            __builtin_amdgcn_s_sleep(1);
          }
        }
        __syncthreads();
      }
      const f16* b0p = &g_H0[t & 3][mrow][kb];        // h0(t)
      const f16* b1p = &g_H1[(t + 3) & 3][mrow][kb];  // h1(t-1)
      half8 la[8], lb[8], lc[8], ld[8];
      CLOAD16(la[0], b0p, 0);   CLOAD16(la[1], b0p, 64);
      CLOAD16(la[2], b0p, 128); CLOAD16(la[3], b0p, 192);
      CLOAD16(la[4], b0p, 256); CLOAD16(la[5], b0p, 320);
      CLOAD16(la[6], b0p, 384); CLOAD16(la[7], b0p, 448);
      CLOAD16(lb[0], b0p, 512); CLOAD16(lb[1], b0p, 576);
      CLOAD16(lb[2], b0p, 640); CLOAD16(lb[3], b0p, 704);
      CLOAD16(lb[4], b0p, 768); CLOAD16(lb[5], b0p, 832);
      CLOAD16(lb[6], b0p, 896); CLOAD16(lb[7], b0p, 960);
      floatx4 aA = {0,0,0,0}, aB = {0,0,0,0};
      VWAIT(8);
      CLOAD16(lc[0], b1p, 0);   CLOAD16(lc[1], b1p, 64);
      CLOAD16(lc[2], b1p, 128); CLOAD16(lc[3], b1p, 192);
      CLOAD16(lc[4], b1p, 256); CLOAD16(lc[5], b1p, 320);
      CLOAD16(lc[6], b1p, 384); CLOAD16(lc[7], b1p, 448);
      #pragma unroll
      for (int cc = 0; cc < 8; ++cc) {
        if (cc & 1) MFMA(aB, la[cc], w1[cc]); else MFMA(aA, la[cc], w1[cc]);
      }
      VWAIT(8);
      CLOAD16(ld[0], b1p, 512); CLOAD16(ld[1], b1p, 576);
      CLOAD16(ld[2], b1p, 640); CLOAD16(ld[3], b1p, 704);
      CLOAD16(ld[4], b1p, 768); CLOAD16(ld[5], b1p, 832);
      CLOAD16(ld[6], b1p, 896); CLOAD16(ld[7], b1p, 960);
      #pragma unroll
      for (int cc = 0; cc < 8; ++cc) {
        if (cc & 1) MFMA(aB, lb[cc], w1[8 + cc]); else MFMA(aA, lb[cc], w1[8 + cc]);
      }
      VWAIT(8);
      #pragma unroll
      for (int cc = 0; cc < 8; ++cc) {
        if (cc & 1) MFMA(aB, lc[cc], w1[16 + cc]); else MFMA(aA, lc[cc], w1[16 + cc]);
      }
      VWAIT(0);
      #pragma unroll
      for (int cc = 0; cc < 8; ++cc) {
        const half8 wb = *(const half8*)(wl1 + cc * 32);
        if (cc & 1) MFMA(aB, ld[cc], wb); else MFMA(aA, ld[cc], wb);
      }
      const floatx4 av = aA + aB;

      float t4[4], t8[4], t12[4];
      #pragma unroll
      for (int r = 0; r < 4; ++r) {
        t4[r]  = __shfl_xor(av[r], 4, 64);
        t8[r]  = __shfl_xor(av[r], 8, 64);
        t12[r] = __shfl_xor(av[r], 12, 64);
      }
      if (r15 < 8) {
        const int q1 = r15 >> 2;
        #pragma unroll
        for (int p = 0; p < 2; ++p) {
          const float vi = (q1 ? t4[2+p]  : (float)av[p]) + bi;
          const float vf = (q1 ? (float)av[2+p] : t4[p])  + bf;
          const float vg = (q1 ? t12[2+p] : t8[p])        + bg;
          const float vo = (q1 ? t8[2+p]  : t12[p])       + bo;
          const float cn = sigm(vf) * creg[p] + sigm(vi) * tanh_(vg);
          const float hn = sigm(vo) * tanh_(cn);
          creg[p] = cn;
          const int rw = g4 * 4 + 2 * q1 + p;
          sh_h[wv][rw][r15 & 3] = (f16)hn;
          sh_c[wv][rw][r15 & 3] = cn;
        }
      }
      if (lane < 16) {
        const u64 hv = *(const u64*)&sh_h[wv][lane][0];
        CSTORE8(&g_H1[t & 3][wv * 16 + lane][j0], hv);
        const floatx4 cv = *(const floatx4*)&sh_c[wv][lane][0];
        CSTORE16(&g_C1[t & 3][wv * 16 + lane][j0], cv);
      }
      VWAIT(0);
      __syncthreads();
      if (tid == 0) sig_flag(wg, base + 2 + (u32)t);
    }

  } else {
    // ================= OUT writers (32 WGs, 2 batch rows each) =================
    const int row = (wg - 192) * 2 + (tid >> 7);
    const int q = tid & 127;
    __syncthreads();
    if (tid == 0) sig_flag(wg, base + 1);
    for (int t = 0; t < NS; ++t) {
      {
        const u32 T = base + 2 + (u32)t;   // L1 done step t
        if (tid < 64) {
          for (;;) {
            const u32 fa = ld_flag(64 + tid);
            const u32 fb = ld_flag(128 + tid);
            if (__all(((int)(fa - T) >= 0) & ((int)(fb - T) >= 0))) break;
            __builtin_amdgcn_s_sleep(1);
          }
        }
        __syncthreads();
      }
      u64 hv; floatx4 cv;
      CLOAD8(hv, &g_H1[t & 3][row][q * 4]);
      CLOADF4(cv, &g_C1[t & 3][row][q * 4]);
      VWAIT(0);
      union { u64 u; f16 h[4]; } U; U.u = hv;
      floatx4 hf = { (float)U.h[0], (float)U.h[1], (float)U.h[2], (float)U.h[3] };
      const size_t o1 = (size_t)row * NS * NH + (size_t)t * NH + q * 4;
      *(floatx4*)&out[o1] = hf;
      *(floatx4*)&out[(size_t)NB * NS * NH + o1] = cv;
      if (t == NS - 1) {
        const size_t o2 = (size_t)2 * NB * NS * NH + (size_t)row * NH + q * 4;
        *(floatx4*)&out[o2] = hf;
        *(floatx4*)&out[o2 + (size_t)NB * NH] = cv;
      }
      __syncthreads();
      if (tid == 0) sig_flag(wg, base + 2 + (u32)t);
    }
  }
}

extern "C" void kernel_launch(void* const* d_in, const int* in_sizes, int n_in,
                              void* d_out, int out_size, void* d_ws, size_t ws_size,
                              hipStream_t stream) {
  (void)in_sizes; (void)n_in; (void)d_ws; (void)ws_size; (void)out_size;
  lstm_persist<<<dim3(NWG), dim3(256), 0, stream>>>(
      (const float*)d_in[0],
      (const float*)d_in[1], (const float*)d_in[2],
      (const float*)d_in[3], (const float*)d_in[4],
      (const float*)d_in[5], (const float*)d_in[6],
      (const float*)d_in[7], (const float*)d_in[8],
      (float*)d_out);
}